// Round 14
// baseline (543.658 us; speedup 1.0000x reference)
//
#include <hip/hip_runtime.h>
#include <stdint.h>

typedef unsigned short u16;
typedef __attribute__((ext_vector_type(4))) short s16x4;
typedef __attribute__((ext_vector_type(8))) short short8;
typedef __attribute__((ext_vector_type(4))) float f32x4;
typedef __attribute__((ext_vector_type(16))) float f32x16;

// ---------- bf16 helpers (RNE) ----------
static __device__ __forceinline__ u16 f2bf(float f) {
    union { float f; uint32_t u; } c; c.f = f;
    uint32_t u = c.u;
    u += 0x7FFFu + ((u >> 16) & 1u);
    return (u16)(u >> 16);
}

// ---------- problem constants ----------
#define D_IN   2048
#define D_OUT  2048
#define MTOT   32768   // B*T
#define BK     64
#define NTM    32      // main K-tiles; tile 32 = LoRA tail

// Fragment-linear layouts (32x32x16 fragments, 1 KB = 64 lanes x 16 B):
//   frag (blk, ks): lane l holds row blk*32+(l&31), cols ks*16+(l>>5)*8 .. +7
//   Wb: [np 0..15][kt 0..31][frag = nb*4+ks, nb 0..3][lane*8+sub]
//   Bp: [a][np 0..15][frag][lane*8+sub]
//   xa: [mp 0..255][frag = mb*4+ks][lane*8+sub]

__device__ __forceinline__ void gload16(const u16* g, u16* l) {
    __builtin_amdgcn_global_load_lds(
        (const __attribute__((address_space(1))) void*)g,
        (__attribute__((address_space(3))) void*)l, 16, 0, 0);
}

// ---------- fused tiny preps: cast W (frag-order), build Apad, build Bpad (frag-order) ----------
__global__ __launch_bounds__(256) void k_prep(
    const float* __restrict__ W, const float* __restrict__ A, const float* __restrict__ Bm,
    u16* __restrict__ Wb, u16* __restrict__ Ap, u16* __restrict__ Bp)
{
    const int b = blockIdx.x, tid = threadIdx.x;
    if (b < 2048) {                       // W cast -> fragment order (128-col n-panels)
        int i = (b * 256 + tid) * 8;
        int n = i >> 11, c = i & 2047;
        const float4* p = (const float4*)(W + i);
        float4 v0 = p[0], v1 = p[1];
        short8 o;
        o[0]=f2bf(v0.x); o[1]=f2bf(v0.y); o[2]=f2bf(v0.z); o[3]=f2bf(v0.w);
        o[4]=f2bf(v1.x); o[5]=f2bf(v1.y); o[6]=f2bf(v1.z); o[7]=f2bf(v1.w);
        const int np = n >> 7, kt = c >> 6, nb = (n & 127) >> 5, ks = (c >> 4) & 3;
        const int fl = (n & 31) + (((c >> 3) & 1) << 5);
        *(short8*)(Wb + (((((size_t)(np << 5) + kt) << 4) + (nb << 2) + ks) << 9) + (fl << 3)) = o;
    } else if (b < 6144) {                // Apad (a,64,d) row-major, rows 16..63 zero (for k_xa)
        int i = (b - 2048) * 256 + tid;
        int d = i & 2047, r = (i >> 11) & 63, a = i >> 17;
        Ap[i] = (r < 16) ? f2bf(A[(((a << 4) + r) << 11) + d]) : (u16)0;
    } else {                              // Bpad (a,n,64) -> fragment order, cols 16..63 zero
        int i = (b - 6144) * 256 + tid;
        int j = i & 63, n = (i >> 6) & 2047, a = i >> 17;
        float v = (j < 16) ? Bm[((((a << 11) + n)) << 4) + j] : 0.0f;
        const int np = n >> 7, nb = (n & 127) >> 5, ks = j >> 4;
        const int fl = (n & 31) + (((j >> 3) & 1) << 5), sub = j & 7;
        Bp[((size_t)a << 17) + ((((np << 4) + (nb << 2) + ks)) << 9) + (fl << 3) + sub] = f2bf(v);
    }
}

// ---------- fused: x fp32 -> xb bf16 AND xa = s*(x @ Apad^T) (xa written frag-order) ----------
__global__ __launch_bounds__(256) void k_cast_x_xa(
    const float* __restrict__ x, const u16* __restrict__ Ap,
    const float* __restrict__ scal, const int* __restrict__ aidx,
    u16* __restrict__ xb, u16* __restrict__ xa)
{
    __shared__ __align__(16) u16 Xs[128 * BK];
    __shared__ __align__(16) u16 Ps[64 * BK];
    const int tid = threadIdx.x, lane = tid & 63, wid = tid >> 6;
    const int m0 = blockIdx.x << 7;
    const int a = aidx[m0 >> 11];
    const float s = scal[a];
    const int wr = wid >> 1, wc = wid & 1;
    const int arow = (wr << 6) + (lane & 15);
    const int brow = (wc << 5) + (lane & 15);
    const int scol = ((lane & 7) ^ (lane >> 3)) << 3;

    f32x4 acc[4][2];
    #pragma unroll
    for (int i = 0; i < 4; ++i) { acc[i][0] = 0.f; acc[i][1] = 0.f; }

    const int xrow_l = tid >> 4;
    const int xcol   = (tid & 15) << 2;
    const int wslot  = (tid & 15) >> 1;
    const int wsub   = (tid & 1) << 2;

    const u16* apg = Ap + ((size_t)a << 17);
    const u16* gP[2]; u16* lP[2];
    #pragma unroll
    for (int it = 0; it < 2; ++it) {
        const int chunk = (wid << 1) + it;
        const int row = (chunk << 3) + (lane >> 3);
        gP[it] = apg + ((size_t)row << 11) + scol;
        lP[it] = Ps + (chunk << 9) + (lane << 3);
    }

    for (int kt = 0; kt < NTM; ++kt) {
        const int k0 = kt << 6;
        float4 xv[8];
        #pragma unroll
        for (int r = 0; r < 8; ++r)
            xv[r] = *(const float4*)(x + ((size_t)(m0 + (r << 4) + xrow_l) << 11) + k0 + xcol);
        #pragma unroll
        for (int r = 0; r < 8; ++r) {
            const int row = (r << 4) + xrow_l;
            s16x4 c4;
            c4[0]=f2bf(xv[r].x); c4[1]=f2bf(xv[r].y); c4[2]=f2bf(xv[r].z); c4[3]=f2bf(xv[r].w);
            *(s16x4*)(Xs + (row << 6) + ((wslot ^ (row & 7)) << 3) + wsub) = c4;
            *(s16x4*)(xb + ((size_t)(m0 + row) << 11) + k0 + xcol) = c4;
        }
        gload16(gP[0] + k0, lP[0]);
        gload16(gP[1] + k0, lP[1]);
        asm volatile("s_waitcnt vmcnt(0)" ::: "memory");
        __syncthreads();
        #pragma unroll
        for (int kk = 0; kk < 2; ++kk) {
            const int sl = ((kk << 2) + (lane >> 4)) ^ (lane & 7);
            short8 af[4], bv[2];
            #pragma unroll
            for (int mi = 0; mi < 4; ++mi)
                af[mi] = *(const short8*)(Xs + ((arow + mi * 16) << 6) + (sl << 3));
            #pragma unroll
            for (int ni = 0; ni < 2; ++ni)
                bv[ni] = *(const short8*)(Ps + ((brow + ni * 16) << 6) + (sl << 3));
            #pragma unroll
            for (int mi = 0; mi < 4; ++mi)
                #pragma unroll
                for (int ni = 0; ni < 2; ++ni)
                    acc[mi][ni] = __builtin_amdgcn_mfma_f32_16x16x32_bf16(af[mi], bv[ni], acc[mi][ni], 0, 0, 0);
        }
        __syncthreads();
    }

    // epilogue -> xa in FRAGMENT order (128-row m-panels)
    #pragma unroll
    for (int mi = 0; mi < 4; ++mi) {
        #pragma unroll
        for (int ni = 0; ni < 2; ++ni) {
            const int cc = (wc << 5) + ni * 16 + (lane & 15);
            #pragma unroll
            for (int rr = 0; rr < 4; ++rr) {
                const int mm = m0 + (wr << 6) + mi * 16 + ((lane >> 4) << 2) + rr;
                const int p = mm >> 7, mb = (mm & 127) >> 5, ks = cc >> 4;
                const int fl = (mm & 31) + (((cc >> 3) & 1) << 5), sub = cc & 7;
                xa[(((size_t)(p << 4) + (mb << 2) + ks) << 9) + (fl << 3) + sub] =
                    f2bf(acc[mi][ni][rr] * s);
            }
        }
    }
}

// ---------- main GEMM: 128x128 tile, BK=64, 4 waves, frag-linear LDS, 64 KB dbuf
// -> 2 blocks/CU (m114 cross-block overlap) + counted vmcnt(8) + raw barriers ----------
__global__ __launch_bounds__(256, 2) void k_gemm(
    const u16* __restrict__ xb, const u16* __restrict__ Wb,
    const u16* __restrict__ xa, const u16* __restrict__ Bp,
    const int* __restrict__ aidx, float* __restrict__ out)
{
    __shared__ __align__(16) u16 LDS[2 * 16384];   // [buf][A 16KB | B 16KB] = 64 KB
    const int tid = threadIdx.x, lane = tid & 63, wid = tid >> 6;

    // XCD-aware bijective swizzle (4096 blocks, 512/XCD chunk; n-minor -> xb panel reuse)
    const int newbid = (blockIdx.x & 7) * 512 + (blockIdx.x >> 3);
    const int bm = newbid >> 4, bn = newbid & 15;
    const int m0 = bm << 7, n0 = bn << 7;
    const int wr = wid >> 1, wc = wid & 1;          // 2x2 wave grid, wave tile 64x64
    const int a = aidx[m0 >> 11];

    f32x16 acc[2][2];
    #pragma unroll
    for (int i = 0; i < 2; ++i)
        #pragma unroll
        for (int j = 0; j < 2; ++j)
            #pragma unroll
            for (int r = 0; r < 16; ++r) acc[i][j][r] = 0.0f;

    // staging: wave wid stages A frag (mb=wid, ks=j) + B frag (nb=wid, ks=j)
    const u16* sA  = xb + ((size_t)(m0 + (wid << 5) + (lane & 31)) << 11) + ((lane >> 5) << 3);
    const u16* sB  = Wb + ((((size_t)(bn << 5) << 4) + (wid << 2)) << 9) + (lane << 3);
    const u16* sTA = xa + (((size_t)(bm << 4) + (wid << 2)) << 9) + (lane << 3);
    const u16* sTB = Bp + ((size_t)a << 17) + (((size_t)(bn << 4) + (wid << 2)) << 9) + (lane << 3);
    const int dbase = ((wid << 2) << 9) + (lane << 3);

    #define STAGE(tt, bb) do {                                                      \
        if ((tt) < NTM) {                                                           \
            const u16* a_ = sA + ((tt) << 6);                                       \
            const u16* b_ = sB + ((size_t)(tt) << 13);                              \
            _Pragma("unroll")                                                       \
            for (int j = 0; j < 4; ++j) {                                           \
                gload16(a_ + (j << 4), &LDS[((bb) << 14) + dbase + (j << 9)]);      \
                gload16(b_ + (j << 9), &LDS[((bb) << 14) + 8192 + dbase + (j << 9)]); \
            }                                                                       \
        } else {                                                                    \
            _Pragma("unroll")                                                       \
            for (int j = 0; j < 4; ++j) {                                           \
                gload16(sTA + (j << 9), &LDS[((bb) << 14) + dbase + (j << 9)]);     \
                gload16(sTB + (j << 9), &LDS[((bb) << 14) + 8192 + dbase + (j << 9)]); \
            }                                                                       \
        } } while (0)

    short8 afP[2], bvP[2], afQ[2], bvQ[2];

    // fragment-linear reads: base + compile-time frag offset + lane*16B -> 0 conflicts
    #define RD(S, c_, ks_) do { _Pragma("unroll")                                   \
        for (int mi = 0; mi < 2; ++mi)                                              \
            af##S[mi] = *(const short8*)&LDS[((c_) << 14) +                         \
                ((((wr << 1) + mi) << 2) + (ks_) << 9) + (lane << 3)];              \
        _Pragma("unroll")                                                           \
        for (int i = 0; i < 2; ++i)                                                 \
            bv##S[i] = *(const short8*)&LDS[((c_) << 14) + 8192 +                   \
                ((((wc << 1) + i) << 2) + (ks_) << 9) + (lane << 3)];               \
        } while (0)

    #define BAR __builtin_amdgcn_s_barrier()
    #define LGK(n) do { asm volatile("s_waitcnt lgkmcnt(" #n ")" ::: "memory");     \
                        __builtin_amdgcn_sched_barrier(0); } while (0)

    #define MM(S) do { __builtin_amdgcn_s_setprio(1); _Pragma("unroll")             \
        for (int mi = 0; mi < 2; ++mi) _Pragma("unroll")                            \
        for (int i = 0; i < 2; ++i)                                                 \
            acc[mi][i] = __builtin_amdgcn_mfma_f32_32x32x16_bf16(                   \
                af##S[mi], bv##S[i], acc[mi][i], 0, 0, 0);                          \
        __builtin_amdgcn_s_setprio(0); } while (0)

    // prologue: stage tile 0 -> buf 0
    STAGE(0, 0);

    for (int t = 0; t <= NTM; ++t) {
        const int c = t & 1;
        if (t < NTM) {
            STAGE(t + 1, c ^ 1);                           // incl. LoRA tile 32
            asm volatile("s_waitcnt vmcnt(8)" ::: "memory"); // retire tile t only
        } else {
            asm volatile("s_waitcnt vmcnt(0)" ::: "memory");
        }
        BAR;
        RD(P, c, 0); RD(Q, c, 1);
        LGK(4); MM(P);
        RD(P, c, 2);
        LGK(4); MM(Q);
        RD(Q, c, 3);
        LGK(4); MM(P);
        LGK(0); MM(Q);
        BAR;
    }

    #undef MM
    #undef LGK
    #undef BAR
    #undef RD
    #undef STAGE

    // epilogue: 32x32 C layout — col = lane&31, row = (reg&3) + 8*(reg>>2) + 4*(lane>>5)
    const int l31 = lane & 31, h5 = lane >> 5;
    #pragma unroll
    for (int mi = 0; mi < 2; ++mi) {
        #pragma unroll
        for (int i = 0; i < 2; ++i) {
            const int nn = n0 + (wc << 6) + (i << 5) + l31;
            #pragma unroll
            for (int r = 0; r < 16; ++r) {
                const int row = (r & 3) + ((r >> 2) << 3) + (h5 << 2);
                const int mm = m0 + (wr << 6) + (mi << 5) + row;
                out[((size_t)mm << 11) + nn] = acc[mi][i][r];
            }
        }
    }
}

extern "C" void kernel_launch(void* const* d_in, const int* in_sizes, int n_in,
                              void* d_out, int out_size, void* d_ws, size_t ws_size,
                              hipStream_t stream) {
    const float* x  = (const float*)d_in[0];
    const float* W  = (const float*)d_in[1];
    const float* A  = (const float*)d_in[2];
    const float* Bm = (const float*)d_in[3];
    const float* sc = (const float*)d_in[4];
    const int* aidx = (const int*)d_in[5];
    float* out = (float*)d_out;

    // ws layout (bytes): xb 128MiB | Wb 8MiB | Apad 2MiB | Bp 2MiB | xa 4MiB = 144 MiB
    char* ws = (char*)d_ws;
    u16* xb = (u16*)(ws);
    u16* Wb = (u16*)(ws + 134217728);
    u16* Ap = (u16*)(ws + 134217728 + 8388608);
    u16* Bp = (u16*)(ws + 134217728 + 8388608 + 2097152);
    u16* xa = (u16*)(ws + 134217728 + 8388608 + 2097152 + 2097152);

    hipLaunchKernelGGL(k_prep,      dim3(10240), dim3(256), 0, stream, W, A, Bm, Wb, Ap, Bp);
    hipLaunchKernelGGL(k_cast_x_xa, dim3(256),   dim3(256), 0, stream, x, Ap, sc, aidx, xb, xa);
    hipLaunchKernelGGL(k_gemm,      dim3(4096),  dim3(256), 0, stream, xb, Wb, xa, Bp, aidx, out);
}

// Round 15
// 474.621 us; speedup vs baseline: 1.1455x; 1.1455x over previous
//
#include <hip/hip_runtime.h>
#include <stdint.h>

typedef unsigned short u16;
typedef __attribute__((ext_vector_type(4))) short s16x4;
typedef __attribute__((ext_vector_type(8))) short short8;
typedef __attribute__((ext_vector_type(4))) float f32x4;
typedef __attribute__((ext_vector_type(16))) float f32x16;

// ---------- bf16 helpers (RNE) ----------
static __device__ __forceinline__ u16 f2bf(float f) {
    union { float f; uint32_t u; } c; c.f = f;
    uint32_t u = c.u;
    u += 0x7FFFu + ((u >> 16) & 1u);
    return (u16)(u >> 16);
}

// ---------- problem constants ----------
#define D_IN   2048
#define D_OUT  2048
#define MTOT   32768   // B*T
#define BK     64
#define NTM    32      // main K-tiles; tile 32 = LoRA tail

// Fragment-linear layouts (32x32x16 fragments, 1 KB = 64 lanes x 16 B):
//   frag (blk, ks): lane l holds row blk*32+(l&31), cols ks*16+(l>>5)*8 .. +7
//   Wb: [np 0..7][kt 0..31][frag = nb*4+ks, nb 0..7][lane*8+sub]
//   Bp: [a][np 0..7][frag][lane*8+sub]
//   xa: [mp 0..127][frag = mb*4+ks][lane*8+sub]

__device__ __forceinline__ void gload16(const u16* g, u16* l) {
    __builtin_amdgcn_global_load_lds(
        (const __attribute__((address_space(1))) void*)g,
        (__attribute__((address_space(3))) void*)l, 16, 0, 0);
}

// ---------- fused tiny preps: cast W (frag-order), build Apad, build Bpad (frag-order) ----------
__global__ __launch_bounds__(256) void k_prep(
    const float* __restrict__ W, const float* __restrict__ A, const float* __restrict__ Bm,
    u16* __restrict__ Wb, u16* __restrict__ Ap, u16* __restrict__ Bp)
{
    const int b = blockIdx.x, tid = threadIdx.x;
    if (b < 2048) {                       // W cast -> fragment order (256-col n-panels)
        int i = (b * 256 + tid) * 8;
        int n = i >> 11, c = i & 2047;
        const float4* p = (const float4*)(W + i);
        float4 v0 = p[0], v1 = p[1];
        short8 o;
        o[0]=f2bf(v0.x); o[1]=f2bf(v0.y); o[2]=f2bf(v0.z); o[3]=f2bf(v0.w);
        o[4]=f2bf(v1.x); o[5]=f2bf(v1.y); o[6]=f2bf(v1.z); o[7]=f2bf(v1.w);
        const int np = n >> 8, kt = c >> 6, nb = (n & 255) >> 5, ks = (c >> 4) & 3;
        const int fl = (n & 31) + (((c >> 3) & 1) << 5);
        *(short8*)(Wb + (((size_t)(np << 5) + kt) << 14) + (((nb << 2) + ks) << 9) + (fl << 3)) = o;
    } else if (b < 6144) {                // Apad (a,64,d) row-major, rows 16..63 zero (for k_xa)
        int i = (b - 2048) * 256 + tid;
        int d = i & 2047, r = (i >> 11) & 63, a = i >> 17;
        Ap[i] = (r < 16) ? f2bf(A[(((a << 4) + r) << 11) + d]) : (u16)0;
    } else {                              // Bpad (a,n,64) -> fragment order, cols 16..63 zero
        int i = (b - 6144) * 256 + tid;
        int j = i & 63, n = (i >> 6) & 2047, a = i >> 17;
        float v = (j < 16) ? Bm[((((a << 11) + n)) << 4) + j] : 0.0f;
        const int np = n >> 8, nb = (n & 255) >> 5, ks = j >> 4;
        const int fl = (n & 31) + (((j >> 3) & 1) << 5), sub = j & 7;
        Bp[((size_t)a << 17) + ((size_t)np << 14) + (((nb << 2) + ks) << 9) + (fl << 3) + sub] = f2bf(v);
    }
}

// ---------- fused: x fp32 -> xb bf16 AND xa = s*(x @ Apad^T) (xa written frag-order) ----------
__global__ __launch_bounds__(256) void k_cast_x_xa(
    const float* __restrict__ x, const u16* __restrict__ Ap,
    const float* __restrict__ scal, const int* __restrict__ aidx,
    u16* __restrict__ xb, u16* __restrict__ xa)
{
    __shared__ __align__(16) u16 Xs[128 * BK];
    __shared__ __align__(16) u16 Ps[64 * BK];
    const int tid = threadIdx.x, lane = tid & 63, wid = tid >> 6;
    const int m0 = blockIdx.x << 7;
    const int a = aidx[m0 >> 11];
    const float s = scal[a];
    const int wr = wid >> 1, wc = wid & 1;
    const int arow = (wr << 6) + (lane & 15);
    const int brow = (wc << 5) + (lane & 15);
    const int scol = ((lane & 7) ^ (lane >> 3)) << 3;

    f32x4 acc[4][2];
    #pragma unroll
    for (int i = 0; i < 4; ++i) { acc[i][0] = 0.f; acc[i][1] = 0.f; }

    const int xrow_l = tid >> 4;
    const int xcol   = (tid & 15) << 2;
    const int wslot  = (tid & 15) >> 1;
    const int wsub   = (tid & 1) << 2;

    const u16* apg = Ap + ((size_t)a << 17);
    const u16* gP[2]; u16* lP[2];
    #pragma unroll
    for (int it = 0; it < 2; ++it) {
        const int chunk = (wid << 1) + it;
        const int row = (chunk << 3) + (lane >> 3);
        gP[it] = apg + ((size_t)row << 11) + scol;
        lP[it] = Ps + (chunk << 9) + (lane << 3);
    }

    for (int kt = 0; kt < NTM; ++kt) {
        const int k0 = kt << 6;
        float4 xv[8];
        #pragma unroll
        for (int r = 0; r < 8; ++r)
            xv[r] = *(const float4*)(x + ((size_t)(m0 + (r << 4) + xrow_l) << 11) + k0 + xcol);
        #pragma unroll
        for (int r = 0; r < 8; ++r) {
            const int row = (r << 4) + xrow_l;
            s16x4 c4;
            c4[0]=f2bf(xv[r].x); c4[1]=f2bf(xv[r].y); c4[2]=f2bf(xv[r].z); c4[3]=f2bf(xv[r].w);
            *(s16x4*)(Xs + (row << 6) + ((wslot ^ (row & 7)) << 3) + wsub) = c4;
            *(s16x4*)(xb + ((size_t)(m0 + row) << 11) + k0 + xcol) = c4;
        }
        gload16(gP[0] + k0, lP[0]);
        gload16(gP[1] + k0, lP[1]);
        asm volatile("s_waitcnt vmcnt(0)" ::: "memory");
        __syncthreads();
        #pragma unroll
        for (int kk = 0; kk < 2; ++kk) {
            const int sl = ((kk << 2) + (lane >> 4)) ^ (lane & 7);
            short8 af[4], bv[2];
            #pragma unroll
            for (int mi = 0; mi < 4; ++mi)
                af[mi] = *(const short8*)(Xs + ((arow + mi * 16) << 6) + (sl << 3));
            #pragma unroll
            for (int ni = 0; ni < 2; ++ni)
                bv[ni] = *(const short8*)(Ps + ((brow + ni * 16) << 6) + (sl << 3));
            #pragma unroll
            for (int mi = 0; mi < 4; ++mi)
                #pragma unroll
                for (int ni = 0; ni < 2; ++ni)
                    acc[mi][ni] = __builtin_amdgcn_mfma_f32_16x16x32_bf16(af[mi], bv[ni], acc[mi][ni], 0, 0, 0);
        }
        __syncthreads();
    }

    // epilogue -> xa in FRAGMENT order (256-row m-panels)
    #pragma unroll
    for (int mi = 0; mi < 4; ++mi) {
        #pragma unroll
        for (int ni = 0; ni < 2; ++ni) {
            const int cc = (wc << 5) + ni * 16 + (lane & 15);
            #pragma unroll
            for (int rr = 0; rr < 4; ++rr) {
                const int mm = m0 + (wr << 6) + mi * 16 + ((lane >> 4) << 2) + rr;
                const int p = mm >> 8, r = mm & 255;
                const int mb = r >> 5, ks = cc >> 4;
                const int fl = (r & 31) + (((cc >> 3) & 1) << 5), sub = cc & 7;
                xa[((size_t)p << 14) + (((mb << 2) + ks) << 9) + (fl << 3) + sub] =
                    f2bf(acc[mi][ni][rr] * s);
            }
        }
    }
}

// ---------- main GEMM: 256x256, BK=64, 8 waves (2M x 4N), 32x32x16 MFMA.
// A: LDS frag-linear dbuf (64 KB). B: DIRECT global->reg (no LDS, Wb is frag-order).
// Counted vmcnt(4), counted lgkm(4), 2 raw barriers/tile. ----------
__global__ __launch_bounds__(512, 2) void k_gemm(
    const u16* __restrict__ xb, const u16* __restrict__ Wb,
    const u16* __restrict__ xa, const u16* __restrict__ Bp,
    const int* __restrict__ aidx, float* __restrict__ out)
{
    __shared__ __align__(16) u16 LDS[2 * 16384];   // A only: [buf][8 mb x 4 ks x 1KB] = 64 KB
    const int tid = threadIdx.x, lane = tid & 63, wid = tid >> 6;

    // XCD-aware bijective swizzle (1024 blocks, n-major within XCD chunk)
    const int newbid = (blockIdx.x & 7) * 128 + (blockIdx.x >> 3);
    const int bm = newbid >> 3, bn = newbid & 7;
    const int m0 = bm << 8;
    const int n0 = bn << 8;
    const int wr = wid >> 2, wc = wid & 3;          // wave tile 128(m) x 64(n)
    const int a = aidx[m0 >> 11];

    f32x16 acc[4][2];                               // 4 mb x 2 nb of 32x32
    #pragma unroll
    for (int i = 0; i < 4; ++i)
        #pragma unroll
        for (int j = 0; j < 2; ++j)
            #pragma unroll
            for (int r = 0; r < 16; ++r) acc[i][j][r] = 0.0f;

    // ---- A staging (r13-verified): wave wid stages frags (mb=wid, ks=0..3)
    const u16* sA  = xb + ((size_t)(m0 + (wid << 5) + (lane & 31)) << 11) + ((lane >> 5) << 3);
    const u16* sTA = xa + ((size_t)bm << 14) + ((wid << 2) << 9) + (lane << 3);
    const int dbase = ((wid << 2) << 9) + (lane << 3);

    #define STAGE_A(tt, bb) do {                                                    \
        if ((tt) < NTM) {                                                           \
            const u16* a_ = sA + ((tt) << 6);                                       \
            _Pragma("unroll")                                                       \
            for (int j = 0; j < 4; ++j) gload16(a_ + (j << 4), &LDS[((bb) << 14) + dbase + (j << 9)]); \
        } else {                                                                    \
            _Pragma("unroll")                                                       \
            for (int j = 0; j < 4; ++j) gload16(sTA + (j << 9), &LDS[((bb) << 14) + dbase + (j << 9)]); \
        } } while (0)

    // ---- B direct from global (frag-order): wave needs nb = wc*2 + i, ks = 0..3
    const u16* sB  = Wb + (((size_t)(bn << 5)) << 14) + ((wc << 3) << 9) + (lane << 3);
    const u16* sTB = Bp + ((size_t)a << 17) + ((size_t)bn << 14) + ((wc << 3) << 9) + (lane << 3);
    short8 bv[2][4];

    #define LOADB(tt) do {                                                          \
        if ((tt) < NTM) {                                                           \
            const u16* b_ = sB + ((size_t)(tt) << 14);                              \
            _Pragma("unroll")                                                       \
            for (int i = 0; i < 2; ++i) _Pragma("unroll")                           \
            for (int k = 0; k < 4; ++k)                                             \
                bv[i][k] = *(const short8*)(b_ + (((i << 2) + k) << 9));            \
        } else {                                                                    \
            _Pragma("unroll")                                                       \
            for (int i = 0; i < 2; ++i) _Pragma("unroll")                           \
            for (int k = 0; k < 4; ++k)                                             \
                bv[i][k] = *(const short8*)(sTB + (((i << 2) + k) << 9));           \
        } } while (0)

    short8 afP[4], afQ[4];

    // A fragment reads: pure base + compile-time offset + lane*16B -> 0 conflicts
    #define RD_A(S, c_, ks_) do { _Pragma("unroll")                                 \
        for (int mi = 0; mi < 4; ++mi)                                              \
            af##S[mi] = *(const short8*)&LDS[((c_) << 14) +                         \
                (((((wr << 2) + mi) << 2) + (ks_)) << 9) + (lane << 3)]; } while (0)

    #define BAR __builtin_amdgcn_s_barrier()
    #define LGK(n) do { asm volatile("s_waitcnt lgkmcnt(" #n ")" ::: "memory");     \
                        __builtin_amdgcn_sched_barrier(0); } while (0)

    #define MM(S, ks_) do { __builtin_amdgcn_s_setprio(1); _Pragma("unroll")        \
        for (int mi = 0; mi < 4; ++mi) _Pragma("unroll")                            \
        for (int i = 0; i < 2; ++i)                                                 \
            acc[mi][i] = __builtin_amdgcn_mfma_f32_32x32x16_bf16(                   \
                af##S[mi], bv[i][ks_], acc[mi][i], 0, 0, 0);                        \
        __builtin_amdgcn_s_setprio(0); } while (0)

    // prologue: A(0) -> buf0 [4 vmem], B(0) -> regs [8 vmem]
    STAGE_A(0, 0);
    LOADB(0);

    for (int t = 0; t <= NTM; ++t) {
        const int c = t & 1;
        if (t < NTM) {
            STAGE_A(t + 1, c ^ 1);                          // +4 vmem (incl. LoRA tile 32)
            asm volatile("s_waitcnt vmcnt(4)" ::: "memory"); // retire A(t)+B(t); A(t+1) in flight
        } else {
            asm volatile("s_waitcnt vmcnt(0)" ::: "memory");
        }
        BAR;                                                // A-LDS buf c visible
        RD_A(P, c, 0);
        RD_A(Q, c, 1);
        LGK(4); MM(P, 0);
        RD_A(P, c, 2);
        LGK(4); MM(Q, 1);
        RD_A(Q, c, 3);
        LGK(4); MM(P, 2);
        LGK(0); MM(Q, 3);
        if (t < NTM) LOADB(t + 1);                          // +8 vmem, retired by next vmcnt
        BAR;                                                // buf-c readers done before t+2 writes
    }

    #undef MM
    #undef LGK
    #undef BAR
    #undef RD_A
    #undef LOADB
    #undef STAGE_A

    // epilogue: 32x32 C layout — col = lane&31, row = (reg&3) + 8*(reg>>2) + 4*(lane>>5)
    const int l31 = lane & 31, h5 = lane >> 5;
    #pragma unroll
    for (int mi = 0; mi < 4; ++mi) {
        #pragma unroll
        for (int i = 0; i < 2; ++i) {
            const int nn = n0 + (wc << 6) + (i << 5) + l31;
            #pragma unroll
            for (int r = 0; r < 16; ++r) {
                const int row = (r & 3) + ((r >> 2) << 3) + (h5 << 2);
                const int mm = m0 + (wr << 7) + (mi << 5) + row;
                out[((size_t)mm << 11) + nn] = acc[mi][i][r];
            }
        }
    }
}

extern "C" void kernel_launch(void* const* d_in, const int* in_sizes, int n_in,
                              void* d_out, int out_size, void* d_ws, size_t ws_size,
                              hipStream_t stream) {
    const float* x  = (const float*)d_in[0];
    const float* W  = (const float*)d_in[1];
    const float* A  = (const float*)d_in[2];
    const float* Bm = (const float*)d_in[3];
    const float* sc = (const float*)d_in[4];
    const int* aidx = (const int*)d_in[5];
    float* out = (float*)d_out;

    // ws layout (bytes): xb 128MiB | Wb 8MiB | Apad 2MiB | Bp 2MiB | xa 4MiB = 144 MiB
    char* ws = (char*)d_ws;
    u16* xb = (u16*)(ws);
    u16* Wb = (u16*)(ws + 134217728);
    u16* Ap = (u16*)(ws + 134217728 + 8388608);
    u16* Bp = (u16*)(ws + 134217728 + 8388608 + 2097152);
    u16* xa = (u16*)(ws + 134217728 + 8388608 + 2097152 + 2097152);

    hipLaunchKernelGGL(k_prep,      dim3(10240), dim3(256), 0, stream, W, A, Bm, Wb, Ap, Bp);
    hipLaunchKernelGGL(k_cast_x_xa, dim3(256),   dim3(256), 0, stream, x, Ap, sc, aidx, xb, xa);
    hipLaunchKernelGGL(k_gemm,      dim3(1024),  dim3(512), 0, stream, xb, Wb, xa, Bp, aidx, out);
}

// Round 16
// 380.673 us; speedup vs baseline: 1.4282x; 1.2468x over previous
//
#include <hip/hip_runtime.h>
#include <stdint.h>

typedef unsigned short u16;
typedef __attribute__((ext_vector_type(4))) short s16x4;
typedef __attribute__((ext_vector_type(8))) short short8;
typedef __attribute__((ext_vector_type(4))) float f32x4;

// ---------- bf16 helpers (RNE) ----------
static __device__ __forceinline__ u16 f2bf(float f) {
    union { float f; uint32_t u; } c; c.f = f;
    uint32_t u = c.u;
    u += 0x7FFFu + ((u >> 16) & 1u);
    return (u16)(u >> 16);
}

// ---------- problem constants ----------
#define D_IN   2048
#define D_OUT  2048
#define MTOT   32768   // B*T
#define BK     64
#define NTM    32      // main K-tiles; tile 32 = LoRA tail

// async global->LDS, 16B/lane; LDS dest = wavebase + lane*16 (linear)
__device__ __forceinline__ void gload16(const u16* g, u16* l) {
    __builtin_amdgcn_global_load_lds(
        (const __attribute__((address_space(1))) void*)g,
        (__attribute__((address_space(3))) void*)l, 16, 0, 0);
}

// ---------- fused tiny preps (r9 layouts): cast W row-major, Apad row-major, Bpad row-major ----------
__global__ __launch_bounds__(256) void k_prep(
    const float* __restrict__ W, const float* __restrict__ A, const float* __restrict__ Bm,
    u16* __restrict__ Wb, u16* __restrict__ Ap, u16* __restrict__ Bp)
{
    const int b = blockIdx.x, tid = threadIdx.x;
    if (b < 2048) {                       // W cast: 4M elems, 8/thread
        int i = (b * 256 + tid) * 8;
        const float4* p = (const float4*)(W + i);
        float4 v0 = p[0], v1 = p[1];
        short8 o;
        o[0]=f2bf(v0.x); o[1]=f2bf(v0.y); o[2]=f2bf(v0.z); o[3]=f2bf(v0.w);
        o[4]=f2bf(v1.x); o[5]=f2bf(v1.y); o[6]=f2bf(v1.z); o[7]=f2bf(v1.w);
        *(short8*)(Wb + i) = o;
    } else if (b < 6144) {                // Apad (a,64,d), rows 16..63 zero
        int i = (b - 2048) * 256 + tid;
        int d = i & 2047, r = (i >> 11) & 63, a = i >> 17;
        Ap[i] = (r < 16) ? f2bf(A[(((a << 4) + r) << 11) + d]) : (u16)0;
    } else {                              // Bpad (a,n,64), cols 16..63 zero
        int i = (b - 6144) * 256 + tid;
        int j = i & 63, n = (i >> 6) & 2047, a = i >> 17;
        Bp[i] = (j < 16) ? f2bf(Bm[((((a << 11) + n)) << 4) + j]) : (u16)0;
    }
}

// ---------- fused cast+xa, HIGH-OCCUPANCY: 1024 blocks x 32 rows (16 waves/CU) ----------
__global__ __launch_bounds__(256) void k_cast_x_xa(
    const float* __restrict__ x, const u16* __restrict__ Ap,
    const float* __restrict__ scal, const int* __restrict__ aidx,
    u16* __restrict__ xb, u16* __restrict__ xa)
{
    __shared__ __align__(16) u16 Xs[32 * BK];   // 4 KB
    __shared__ __align__(16) u16 Ps[64 * BK];   // 8 KB
    const int tid = threadIdx.x, lane = tid & 63, wid = tid >> 6;
    const int m0 = blockIdx.x << 5;             // 32 rows/block
    const int a = aidx[m0 >> 11];
    const float s = scal[a];
    const int wr = wid >> 1, wc = wid & 1;      // wave: 16 rows x 32 cols of xa
    const int arow = (wr << 4) + (lane & 15);
    const int brow = (wc << 5) + (lane & 15);
    const int scol = ((lane & 7) ^ (lane >> 3)) << 3;

    f32x4 acc[2];
    acc[0] = 0.f; acc[1] = 0.f;

    // x load coords: 2 rounds; round j: row = j*16 + (tid>>4), fp32 col = (tid&15)*4
    const int xrow_l = tid >> 4;
    const int xcol   = (tid & 15) << 2;
    const int wslot  = (tid & 15) >> 1;
    const int wsub   = (tid & 1) << 2;

    const u16* apg = Ap + ((size_t)a << 17);
    const u16* gP[2]; u16* lP[2];
    #pragma unroll
    for (int it = 0; it < 2; ++it) {
        const int chunk = (wid << 1) + it;
        const int row = (chunk << 3) + (lane >> 3);
        gP[it] = apg + ((size_t)row << 11) + scol;
        lP[it] = Ps + (chunk << 9) + (lane << 3);
    }

    for (int kt = 0; kt < NTM; ++kt) {
        const int k0 = kt << 6;
        float4 xv[2];
        #pragma unroll
        for (int j = 0; j < 2; ++j)
            xv[j] = *(const float4*)(x + ((size_t)(m0 + (j << 4) + xrow_l) << 11) + k0 + xcol);
        #pragma unroll
        for (int j = 0; j < 2; ++j) {
            const int row = (j << 4) + xrow_l;
            s16x4 c4;
            c4[0]=f2bf(xv[j].x); c4[1]=f2bf(xv[j].y); c4[2]=f2bf(xv[j].z); c4[3]=f2bf(xv[j].w);
            *(s16x4*)(Xs + (row << 6) + ((wslot ^ (row & 7)) << 3) + wsub) = c4;
            *(s16x4*)(xb + ((size_t)(m0 + row) << 11) + k0 + xcol) = c4;
        }
        gload16(gP[0] + k0, lP[0]);
        gload16(gP[1] + k0, lP[1]);
        asm volatile("s_waitcnt vmcnt(0)" ::: "memory");
        __syncthreads();
        #pragma unroll
        for (int kk = 0; kk < 2; ++kk) {
            const int sl = ((kk << 2) + (lane >> 4)) ^ (lane & 7);
            short8 af = *(const short8*)(Xs + (arow << 6) + (sl << 3));
            #pragma unroll
            for (int ni = 0; ni < 2; ++ni) {
                short8 bv = *(const short8*)(Ps + ((brow + ni * 16) << 6) + (sl << 3));
                acc[ni] = __builtin_amdgcn_mfma_f32_16x16x32_bf16(af, bv, acc[ni], 0, 0, 0);
            }
        }
        __syncthreads();
    }

    // epilogue -> xa row-major (m, 64)
    #pragma unroll
    for (int ni = 0; ni < 2; ++ni) {
        const int cc = (wc << 5) + ni * 16 + (lane & 15);
        #pragma unroll
        for (int rr = 0; rr < 4; ++rr) {
            const int mm = m0 + (wr << 4) + ((lane >> 4) << 2) + rr;
            xa[((size_t)mm << 6) + cc] = f2bf(acc[ni][rr] * s);
        }
    }
}

// ---------- main GEMM (r9 verbatim — best measured): 256x256, BK=64, 8 waves,
// 4-phase/K-tile, half-tile staging (1/phase), counted vmcnt(4), proven swizzle ----------
__global__ __launch_bounds__(512, 2) void k_gemm(
    const u16* __restrict__ xb, const u16* __restrict__ Wb,
    const u16* __restrict__ xa, const u16* __restrict__ Bp,
    const int* __restrict__ aidx, float* __restrict__ out)
{
    __shared__ __align__(16) u16 LDS[2 * 32768];   // [buf][A 256x64 | B 256x64] = 128 KB
    const int tid = threadIdx.x, lane = tid & 63, wid = tid >> 6;

    const int newbid = (blockIdx.x & 7) * 128 + (blockIdx.x >> 3);
    const int bm = newbid >> 3, bn = newbid & 7;
    const int m0 = bm << 8, n0 = bn << 8;
    const int wr = wid >> 2, wc = wid & 3;
    const int a = aidx[m0 >> 11];

    f32x4 acc[8][4];
    #pragma unroll
    for (int i = 0; i < 8; ++i)
        #pragma unroll
        for (int j = 0; j < 4; ++j) acc[i][j] = 0.0f;

    const int sc = ((tid & 7) ^ ((tid >> 3) & 7)) << 3;
    const int srw = tid >> 3;

    const int sl0 = (((lane >> 4)    ) ^ (lane & 7)) << 3;
    const int sl1 = (((lane >> 4) + 4) ^ (lane & 7)) << 3;
    const int aRowBase = (wr << 7) + (lane & 15);
    const int bRowBase = (wc << 6) + (lane & 15);

    short8 af[4][2], bv[4][2];

    auto STG = [&](const u16* ptr, int stride, int rowbase, int kofs, int ldsofs) {
        const u16* s_ = ptr + ((size_t)(rowbase + srw)) * stride + kofs + sc;
        gload16(s_,                          &LDS[ldsofs + (tid << 3)]);
        gload16(s_ + ((size_t)stride << 6),  &LDS[ldsofs + 4096 + (tid << 3)]);
    };
    auto SA = [&](int tt, int h) {
        const int lo = ((tt & 1) << 15) + (h << 13);
        if (tt < NTM) STG(xb, 2048, m0 + (h << 7), tt << 6, lo);
        else          STG(xa, 64,   m0 + (h << 7), 0,       lo);
    };
    auto SB = [&](int tt, int h) {
        const int lo = ((tt & 1) << 15) + 16384 + (h << 13);
        if (tt < NTM) STG(Wb, 2048, n0 + (h << 7), tt << 6, lo);
        else          STG(Bp, 64,   (a << 11) + n0 + (h << 7), 0, lo);
    };

    #define BAR  __builtin_amdgcn_s_barrier()
    #define LGK0 do { asm volatile("s_waitcnt lgkmcnt(0)" ::: "memory"); \
                      __builtin_amdgcn_sched_barrier(0); } while (0)

    #define RDA(c_, mq_) do { _Pragma("unroll")                                     \
        for (int mi = 0; mi < 4; ++mi) {                                            \
            const int row = aRowBase + ((mq_) << 6) + (mi << 4);                    \
            af[mi][0] = *(const short8*)&LDS[((c_) << 15) + (row << 6) + sl0];      \
            af[mi][1] = *(const short8*)&LDS[((c_) << 15) + (row << 6) + sl1];      \
        } } while (0)

    #define RDB(c_, ni_) do {                                                       \
            const int row = bRowBase + ((ni_) << 4);                                \
            bv[ni_][0] = *(const short8*)&LDS[((c_) << 15) + 16384 + (row << 6) + sl0]; \
            bv[ni_][1] = *(const short8*)&LDS[((c_) << 15) + 16384 + (row << 6) + sl1]; \
        } while (0)

    #define MM(mq_, ns_) do { __builtin_amdgcn_s_setprio(1); _Pragma("unroll")      \
        for (int kk = 0; kk < 2; ++kk) _Pragma("unroll")                            \
        for (int mi = 0; mi < 4; ++mi) _Pragma("unroll")                            \
        for (int j = 0; j < 2; ++j)                                                 \
            acc[(mq_) * 4 + mi][(ns_) * 2 + j] =                                    \
                __builtin_amdgcn_mfma_f32_16x16x32_bf16(af[mi][kk],                 \
                    bv[(ns_) * 2 + j][kk], acc[(mq_) * 4 + mi][(ns_) * 2 + j], 0, 0, 0); \
        __builtin_amdgcn_s_setprio(0); } while (0)

    SA(0, 0); SA(0, 1); SB(0, 0); SB(0, 1); SB(1, 0); SB(1, 1);
    asm volatile("s_waitcnt vmcnt(4)" ::: "memory");
    BAR;

    for (int t = 0; t <= NTM; ++t) {
        const int c = t & 1;
        RDB(c, 0); RDB(c, 1); RDA(c, 0);
        if (t + 1 <= NTM) SA(t + 1, 0);
        BAR; LGK0; MM(0, 0); BAR;
        RDB(c, 2); RDB(c, 3);
        if (t + 1 <= NTM) SA(t + 1, 1);
        BAR; LGK0; MM(0, 1); BAR;
        RDA(c, 1);
        if (t + 2 <= NTM) SB(t + 2, 0);
        BAR; LGK0; MM(1, 0); BAR;
        if (t + 2 <= NTM) SB(t + 2, 1);
        BAR; MM(1, 1);
        if (t < NTM - 1)      asm volatile("s_waitcnt vmcnt(4)" ::: "memory");
        else if (t == NTM - 1) asm volatile("s_waitcnt vmcnt(0)" ::: "memory");
        BAR;
    }

    #undef MM
    #undef RDB
    #undef RDA
    #undef LGK0
    #undef BAR

    #pragma unroll
    for (int mi = 0; mi < 8; ++mi) {
        #pragma unroll
        for (int ni = 0; ni < 4; ++ni) {
            const int nn = n0 + (wc << 6) + ni * 16 + (lane & 15);
            #pragma unroll
            for (int r = 0; r < 4; ++r) {
                const int mm = m0 + (wr << 7) + mi * 16 + ((lane >> 4) << 2) + r;
                out[((size_t)mm << 11) + nn] = acc[mi][ni][r];
            }
        }
    }
}

extern "C" void kernel_launch(void* const* d_in, const int* in_sizes, int n_in,
                              void* d_out, int out_size, void* d_ws, size_t ws_size,
                              hipStream_t stream) {
    const float* x  = (const float*)d_in[0];
    const float* W  = (const float*)d_in[1];
    const float* A  = (const float*)d_in[2];
    const float* Bm = (const float*)d_in[3];
    const float* sc = (const float*)d_in[4];
    const int* aidx = (const int*)d_in[5];
    float* out = (float*)d_out;

    // ws layout (bytes): xb 128MiB | Wb 8MiB | Apad 2MiB | Bp 2MiB | xa 4MiB = 144 MiB
    char* ws = (char*)d_ws;
    u16* xb = (u16*)(ws);
    u16* Wb = (u16*)(ws + 134217728);
    u16* Ap = (u16*)(ws + 134217728 + 8388608);
    u16* Bp = (u16*)(ws + 134217728 + 8388608 + 2097152);
    u16* xa = (u16*)(ws + 134217728 + 8388608 + 2097152 + 2097152);

    hipLaunchKernelGGL(k_prep,      dim3(10240), dim3(256), 0, stream, W, A, Bm, Wb, Ap, Bp);
    hipLaunchKernelGGL(k_cast_x_xa, dim3(1024),  dim3(256), 0, stream, x, Ap, sc, aidx, xb, xa);
    hipLaunchKernelGGL(k_gemm,      dim3(1024),  dim3(512), 0, stream, xb, Wb, xa, Bp, aidx, out);
}

// Round 17
// 369.345 us; speedup vs baseline: 1.4720x; 1.0307x over previous
//
#include <hip/hip_runtime.h>
#include <stdint.h>

typedef unsigned short u16;
typedef __attribute__((ext_vector_type(4))) short s16x4;
typedef __attribute__((ext_vector_type(8))) short short8;
typedef __attribute__((ext_vector_type(4))) float f32x4;

// ---------- bf16 helpers (RNE) ----------
static __device__ __forceinline__ u16 f2bf(float f) {
    union { float f; uint32_t u; } c; c.f = f;
    uint32_t u = c.u;
    u += 0x7FFFu + ((u >> 16) & 1u);
    return (u16)(u >> 16);
}

// ---------- problem constants ----------
#define D_IN   2048
#define D_OUT  2048
#define MTOT   32768   // B*T
#define BK     64
#define NTM    32      // main K-tiles; tile 32 = LoRA tail

// async global->LDS, 16B/lane; LDS dest = wavebase + lane*16 (linear)
__device__ __forceinline__ void gload16(const u16* g, u16* l) {
    __builtin_amdgcn_global_load_lds(
        (const __attribute__((address_space(1))) void*)g,
        (__attribute__((address_space(3))) void*)l, 16, 0, 0);
}

// ---------- MERGED pre-pass: [0,1024) cast x + xa ; [1024,3072) W cast ; [3072,7168) Bp ----------
__global__ __launch_bounds__(256) void k_pre(
    const float* __restrict__ x, const float* __restrict__ W,
    const float* __restrict__ A, const float* __restrict__ Bm,
    const float* __restrict__ scal, const int* __restrict__ aidx,
    u16* __restrict__ xb, u16* __restrict__ Wb, u16* __restrict__ Bp,
    u16* __restrict__ xa)
{
    __shared__ __align__(16) u16 Xs[32 * BK];   // 4 KB
    __shared__ __align__(16) u16 Ps[64 * BK];   // 8 KB
    const int b = blockIdx.x, tid = threadIdx.x;

    if (b >= 1024) {
        if (b < 3072) {                   // W cast: 4M elems, 8/thread
            int i = ((b - 1024) * 256 + tid) * 8;
            const float4* p = (const float4*)(W + i);
            float4 v0 = p[0], v1 = p[1];
            short8 o;
            o[0]=f2bf(v0.x); o[1]=f2bf(v0.y); o[2]=f2bf(v0.z); o[3]=f2bf(v0.w);
            o[4]=f2bf(v1.x); o[5]=f2bf(v1.y); o[6]=f2bf(v1.z); o[7]=f2bf(v1.w);
            *(short8*)(Wb + i) = o;
        } else {                          // Bpad (a,n,64), cols 16..63 zero
            int i = (b - 3072) * 256 + tid;   // over 1048576
            int j = i & 63, n = (i >> 6) & 2047, a = i >> 17;
            Bp[i] = (j < 16) ? f2bf(Bm[((((a << 11) + n)) << 4) + j]) : (u16)0;
        }
        return;
    }

    // ---- cast + xa block: 32 rows of x ----
    const int lane = tid & 63, wid = tid >> 6;
    const int m0 = b << 5;
    const int a = aidx[m0 >> 11];
    const float s = scal[a];
    const int wr = wid >> 1, wc = wid & 1;      // wave: 16 rows x 32 xa-cols
    const int arow = (wr << 4) + (lane & 15);
    const int brow = (wc << 5) + (lane & 15);

    f32x4 acc[2];
    acc[0] = 0.f; acc[1] = 0.f;

    // zero Ps rows 16..63 once (3072 elems, 12/thread)
    {
        s16x4 z; z[0]=0; z[1]=0; z[2]=0; z[3]=0;
        #pragma unroll
        for (int j = 0; j < 3; ++j)
            *(s16x4*)(Ps + 1024 + tid * 12 + j * 4) = z;
    }

    // x coords: 2 rounds; round j: row = j*16 + (tid>>4), fp32 col = (tid&15)*4
    const int xrow_l = tid >> 4;
    const int xcol   = (tid & 15) << 2;
    const int wslot  = (tid & 15) >> 1;
    const int wsub   = (tid & 1) << 2;
    // P-tile coords: rows 0..15 from raw A (L2-resident), same swizzle convention
    const int prow  = tid >> 4;
    const int pcolg = tid & 15;
    const float* Arow = A + ((size_t)((a << 4) + prow) << 11) + (pcolg << 2);
    u16* pdst = Ps + (prow << 6) + ((((pcolg >> 1) ^ (prow & 7))) << 3) + ((pcolg & 1) << 2);

    for (int kt = 0; kt < NTM; ++kt) {
        const int k0 = kt << 6;
        float4 xv[2];
        #pragma unroll
        for (int j = 0; j < 2; ++j)
            xv[j] = *(const float4*)(x + ((size_t)(m0 + (j << 4) + xrow_l) << 11) + k0 + xcol);
        float4 av = *(const float4*)(Arow + k0);
        #pragma unroll
        for (int j = 0; j < 2; ++j) {
            const int row = (j << 4) + xrow_l;
            s16x4 c4;
            c4[0]=f2bf(xv[j].x); c4[1]=f2bf(xv[j].y); c4[2]=f2bf(xv[j].z); c4[3]=f2bf(xv[j].w);
            *(s16x4*)(Xs + (row << 6) + ((wslot ^ (row & 7)) << 3) + wsub) = c4;
            *(s16x4*)(xb + ((size_t)(m0 + row) << 11) + k0 + xcol) = c4;
        }
        {
            s16x4 a4;
            a4[0]=f2bf(av.x); a4[1]=f2bf(av.y); a4[2]=f2bf(av.z); a4[3]=f2bf(av.w);
            *(s16x4*)pdst = a4;
        }
        __syncthreads();
        #pragma unroll
        for (int kk = 0; kk < 2; ++kk) {
            const int sl = ((kk << 2) + (lane >> 4)) ^ (lane & 7);
            short8 af = *(const short8*)(Xs + (arow << 6) + (sl << 3));
            #pragma unroll
            for (int ni = 0; ni < 2; ++ni) {
                short8 bv = *(const short8*)(Ps + ((brow + ni * 16) << 6) + (sl << 3));
                acc[ni] = __builtin_amdgcn_mfma_f32_16x16x32_bf16(af, bv, acc[ni], 0, 0, 0);
            }
        }
        __syncthreads();
    }

    // epilogue -> xa row-major (m, 64)
    #pragma unroll
    for (int ni = 0; ni < 2; ++ni) {
        const int cc = (wc << 5) + ni * 16 + (lane & 15);
        #pragma unroll
        for (int rr = 0; rr < 4; ++rr) {
            const int mm = m0 + (wr << 4) + ((lane >> 4) << 2) + rr;
            xa[((size_t)mm << 6) + cc] = f2bf(acc[ni][rr] * s);
        }
    }
}

// ---------- main GEMM (r16 verbatim — best measured): 256x256, BK=64, 8 waves,
// 4-phase/K-tile, half-tile staging (1/phase), counted vmcnt(4), proven swizzle ----------
__global__ __launch_bounds__(512, 2) void k_gemm(
    const u16* __restrict__ xb, const u16* __restrict__ Wb,
    const u16* __restrict__ xa, const u16* __restrict__ Bp,
    const int* __restrict__ aidx, float* __restrict__ out)
{
    __shared__ __align__(16) u16 LDS[2 * 32768];   // [buf][A 256x64 | B 256x64] = 128 KB
    const int tid = threadIdx.x, lane = tid & 63, wid = tid >> 6;

    const int newbid = (blockIdx.x & 7) * 128 + (blockIdx.x >> 3);
    const int bm = newbid >> 3, bn = newbid & 7;
    const int m0 = bm << 8, n0 = bn << 8;
    const int wr = wid >> 2, wc = wid & 3;
    const int a = aidx[m0 >> 11];

    f32x4 acc[8][4];
    #pragma unroll
    for (int i = 0; i < 8; ++i)
        #pragma unroll
        for (int j = 0; j < 4; ++j) acc[i][j] = 0.0f;

    const int sc = ((tid & 7) ^ ((tid >> 3) & 7)) << 3;
    const int srw = tid >> 3;

    const int sl0 = (((lane >> 4)    ) ^ (lane & 7)) << 3;
    const int sl1 = (((lane >> 4) + 4) ^ (lane & 7)) << 3;
    const int aRowBase = (wr << 7) + (lane & 15);
    const int bRowBase = (wc << 6) + (lane & 15);

    short8 af[4][2], bv[4][2];

    auto STG = [&](const u16* ptr, int stride, int rowbase, int kofs, int ldsofs) {
        const u16* s_ = ptr + ((size_t)(rowbase + srw)) * stride + kofs + sc;
        gload16(s_,                          &LDS[ldsofs + (tid << 3)]);
        gload16(s_ + ((size_t)stride << 6),  &LDS[ldsofs + 4096 + (tid << 3)]);
    };
    auto SA = [&](int tt, int h) {
        const int lo = ((tt & 1) << 15) + (h << 13);
        if (tt < NTM) STG(xb, 2048, m0 + (h << 7), tt << 6, lo);
        else          STG(xa, 64,   m0 + (h << 7), 0,       lo);
    };
    auto SB = [&](int tt, int h) {
        const int lo = ((tt & 1) << 15) + 16384 + (h << 13);
        if (tt < NTM) STG(Wb, 2048, n0 + (h << 7), tt << 6, lo);
        else          STG(Bp, 64,   (a << 11) + n0 + (h << 7), 0, lo);
    };

    #define BAR  __builtin_amdgcn_s_barrier()
    #define LGK0 do { asm volatile("s_waitcnt lgkmcnt(0)" ::: "memory"); \
                      __builtin_amdgcn_sched_barrier(0); } while (0)

    #define RDA(c_, mq_) do { _Pragma("unroll")                                     \
        for (int mi = 0; mi < 4; ++mi) {                                            \
            const int row = aRowBase + ((mq_) << 6) + (mi << 4);                    \
            af[mi][0] = *(const short8*)&LDS[((c_) << 15) + (row << 6) + sl0];      \
            af[mi][1] = *(const short8*)&LDS[((c_) << 15) + (row << 6) + sl1];      \
        } } while (0)

    #define RDB(c_, ni_) do {                                                       \
            const int row = bRowBase + ((ni_) << 4);                                \
            bv[ni_][0] = *(const short8*)&LDS[((c_) << 15) + 16384 + (row << 6) + sl0]; \
            bv[ni_][1] = *(const short8*)&LDS[((c_) << 15) + 16384 + (row << 6) + sl1]; \
        } while (0)

    #define MM(mq_, ns_) do { __builtin_amdgcn_s_setprio(1); _Pragma("unroll")      \
        for (int kk = 0; kk < 2; ++kk) _Pragma("unroll")                            \
        for (int mi = 0; mi < 4; ++mi) _Pragma("unroll")                            \
        for (int j = 0; j < 2; ++j)                                                 \
            acc[(mq_) * 4 + mi][(ns_) * 2 + j] =                                    \
                __builtin_amdgcn_mfma_f32_16x16x32_bf16(af[mi][kk],                 \
                    bv[(ns_) * 2 + j][kk], acc[(mq_) * 4 + mi][(ns_) * 2 + j], 0, 0, 0); \
        __builtin_amdgcn_s_setprio(0); } while (0)

    SA(0, 0); SA(0, 1); SB(0, 0); SB(0, 1); SB(1, 0); SB(1, 1);
    asm volatile("s_waitcnt vmcnt(4)" ::: "memory");
    BAR;

    for (int t = 0; t <= NTM; ++t) {
        const int c = t & 1;
        RDB(c, 0); RDB(c, 1); RDA(c, 0);
        if (t + 1 <= NTM) SA(t + 1, 0);
        BAR; LGK0; MM(0, 0); BAR;
        RDB(c, 2); RDB(c, 3);
        if (t + 1 <= NTM) SA(t + 1, 1);
        BAR; LGK0; MM(0, 1); BAR;
        RDA(c, 1);
        if (t + 2 <= NTM) SB(t + 2, 0);
        BAR; LGK0; MM(1, 0); BAR;
        if (t + 2 <= NTM) SB(t + 2, 1);
        BAR; MM(1, 1);
        if (t < NTM - 1)      asm volatile("s_waitcnt vmcnt(4)" ::: "memory");
        else if (t == NTM - 1) asm volatile("s_waitcnt vmcnt(0)" ::: "memory");
        BAR;
    }

    #undef MM
    #undef RDB
    #undef RDA
    #undef LGK0
    #undef BAR

    #pragma unroll
    for (int mi = 0; mi < 8; ++mi) {
        #pragma unroll
        for (int ni = 0; ni < 4; ++ni) {
            const int nn = n0 + (wc << 6) + ni * 16 + (lane & 15);
            #pragma unroll
            for (int r = 0; r < 4; ++r) {
                const int mm = m0 + (wr << 7) + mi * 16 + ((lane >> 4) << 2) + r;
                out[((size_t)mm << 11) + nn] = acc[mi][ni][r];
            }
        }
    }
}

extern "C" void kernel_launch(void* const* d_in, const int* in_sizes, int n_in,
                              void* d_out, int out_size, void* d_ws, size_t ws_size,
                              hipStream_t stream) {
    const float* x  = (const float*)d_in[0];
    const float* W  = (const float*)d_in[1];
    const float* A  = (const float*)d_in[2];
    const float* Bm = (const float*)d_in[3];
    const float* sc = (const float*)d_in[4];
    const int* aidx = (const int*)d_in[5];
    float* out = (float*)d_out;

    // ws layout (bytes): xb 128MiB | Wb 8MiB | (unused 2MiB) | Bp 2MiB | xa 4MiB
    char* ws = (char*)d_ws;
    u16* xb = (u16*)(ws);
    u16* Wb = (u16*)(ws + 134217728);
    u16* Bp = (u16*)(ws + 134217728 + 8388608 + 2097152);
    u16* xa = (u16*)(ws + 134217728 + 8388608 + 2097152 + 2097152);

    hipLaunchKernelGGL(k_pre,  dim3(7168), dim3(256), 0, stream,
                       x, W, A, Bm, sc, aidx, xb, Wb, Bp, xa);
    hipLaunchKernelGGL(k_gemm, dim3(1024), dim3(512), 0, stream,
                       xb, Wb, xa, Bp, aidx, out);
}